// Round 9
// baseline (100.390 us; speedup 1.0000x reference)
//
#include <hip/hip_runtime.h>
#include <stdint.h>

#define DIM 256
#define NQ 8
#define NLAYERS 3
#define NPAIRS 4

typedef float f32x4 __attribute__((ext_vector_type(4)));
typedef long lng2 __attribute__((ext_vector_type(2)));  // 16 B = two i64 fp8 frags

// ---------------------------------------------------------------------------
// Kernel 1: build U (256x256 complex fp32), barrier-free, one WAVE per basis
// column, one column per 64-thread block. Lane holds 4 amplitudes
// a = r*64 + lane. Wire w <-> bit (7-w) of a: wire0 -> r bit1, wire1 -> r
// bit0 (in-register), wire2..7 -> lane bits 5..0 (shfl_xor).
// Algebra verified rounds 6-8 (passed, absmax unchanged).
// ---------------------------------------------------------------------------
__global__ __launch_bounds__(64) void build_U(const float* __restrict__ params,
                                              float* __restrict__ Ure,
                                              float* __restrict__ Uim) {
  const int lane = threadIdx.x;
  const int col = blockIdx.x;

  float ar[4], ai[4];
#pragma unroll
  for (int r = 0; r < 4; ++r) {
    ar[r] = (r * 64 + lane == col) ? 1.0f : 0.0f;
    ai[r] = 0.0f;
  }

  for (int layer = 0; layer < NLAYERS; ++layer) {
#pragma unroll
    for (int p = 0; p < NPAIRS; ++p) {
      const int base = (layer * NPAIRS + p) * 4;
      const float p0 = params[base + 0], p1 = params[base + 1];
      const float p2 = params[base + 2], p3 = params[base + 3];
      const int czm = (p == 1) ? 32 : (p == 2) ? 8 : 2;   // ctrl / RZ_i bit
      const int txr = (p == 1) ? 16 : (p == 2) ? 4 : 1;   // target xor / bit

      { // RZ(p0) on wire i = 2p
        float s0, c0;
        __sincosf(0.5f * p0, &s0, &c0);
        if (p == 0) {
#pragma unroll
          for (int r = 0; r < 4; ++r) {
            const float sg = (r >= 2) ? s0 : -s0;  // r bit1
            const float nr = ar[r] * c0 - ai[r] * sg;
            ai[r] = ar[r] * sg + ai[r] * c0;
            ar[r] = nr;
          }
        } else {
          const float sg = (lane & czm) ? s0 : -s0;
#pragma unroll
          for (int r = 0; r < 4; ++r) {
            const float nr = ar[r] * c0 - ai[r] * sg;
            ai[r] = ar[r] * sg + ai[r] * c0;
            ar[r] = nr;
          }
        }
      }
      { // RX(p1) on wire j = 2p+1
        float s0, c0;
        __sincosf(0.5f * p1, &s0, &c0);
        if (p == 0) {  // partner r^1
          float nr[4], ni[4];
#pragma unroll
          for (int r = 0; r < 4; ++r) {
            nr[r] = c0 * ar[r] + s0 * ai[r ^ 1];
            ni[r] = c0 * ai[r] - s0 * ar[r ^ 1];
          }
#pragma unroll
          for (int r = 0; r < 4; ++r) { ar[r] = nr[r]; ai[r] = ni[r]; }
        } else {  // partner lane^txr
#pragma unroll
          for (int r = 0; r < 4; ++r) {
            const float pr = __shfl_xor(ar[r], txr);
            const float pi = __shfl_xor(ai[r], txr);
            ar[r] = c0 * ar[r] + s0 * pi;
            ai[r] = c0 * ai[r] - s0 * pr;
          }
        }
      }
      { // CNOT(i -> j)
        if (p == 0) {  // ctrl r bit1: swap amp[2] <-> amp[3]
          const float tr = ar[2], ti = ai[2];
          ar[2] = ar[3]; ai[2] = ai[3];
          ar[3] = tr;    ai[3] = ti;
        } else {
#pragma unroll
          for (int r = 0; r < 4; ++r) {
            const float vr = __shfl_xor(ar[r], txr);
            const float vi = __shfl_xor(ai[r], txr);
            ar[r] = (lane & czm) ? vr : ar[r];
            ai[r] = (lane & czm) ? vi : ai[r];
          }
        }
      }
      { // RZ(p2) on wire j
        float s0, c0;
        __sincosf(0.5f * p2, &s0, &c0);
        if (p == 0) {
#pragma unroll
          for (int r = 0; r < 4; ++r) {
            const float sg = (r & 1) ? s0 : -s0;  // r bit0
            const float nr = ar[r] * c0 - ai[r] * sg;
            ai[r] = ar[r] * sg + ai[r] * c0;
            ar[r] = nr;
          }
        } else {
          const float sg = (lane & txr) ? s0 : -s0;
#pragma unroll
          for (int r = 0; r < 4; ++r) {
            const float nr = ar[r] * c0 - ai[r] * sg;
            ai[r] = ar[r] * sg + ai[r] * c0;
            ar[r] = nr;
          }
        }
      }
      { // RX(p3) on wire j
        float s0, c0;
        __sincosf(0.5f * p3, &s0, &c0);
        if (p == 0) {
          float nr[4], ni[4];
#pragma unroll
          for (int r = 0; r < 4; ++r) {
            nr[r] = c0 * ar[r] + s0 * ai[r ^ 1];
            ni[r] = c0 * ai[r] - s0 * ar[r ^ 1];
          }
#pragma unroll
          for (int r = 0; r < 4; ++r) { ar[r] = nr[r]; ai[r] = ni[r]; }
        } else {
#pragma unroll
          for (int r = 0; r < 4; ++r) {
            const float pr = __shfl_xor(ar[r], txr);
            const float pi = __shfl_xor(ai[r], txr);
            ar[r] = c0 * ar[r] + s0 * pi;
            ai[r] = c0 * ai[r] - s0 * pr;
          }
        }
      }
    }
  }
#pragma unroll
  for (int r = 0; r < 4; ++r) {
    Ure[(r * 64 + lane) * DIM + col] = ar[r];
    Uim[(r * 64 + lane) * DIM + col] = ai[r];
  }
}

// ---------------------------------------------------------------------------
// Kernel 2: A[n][k] = Re(U^H D U)[n][k], now stored as fp8 e4m3 (|A|<=1 so
// no scaling needed; HW cvt is RNE) in PAIRED fragment order so one
// ds_read_b128 yields the A-fragments of TWO k-blocks (t=2tp, 2tp+1):
//   nt=n>>4, c=n&15, t=k>>5, tp=t>>1, pr=t&1, q=(k>>3)&3, j=k&7
//   off = (((nt*4 + tp)*4 + q)*16 + c)*16 + pr*8 + j         (64 KB total)
// In-kernel: lane l=q*16+c reads 16 B at nt*4096 + tp*1024 + l*16; bytes 0-7
// = frag for k-block 2tp, bytes 8-15 = frag for 2tp+1.
// ---------------------------------------------------------------------------
__global__ __launch_bounds__(1024) void build_A(const float* __restrict__ Ure,
                                                const float* __restrict__ Uim,
                                                unsigned char* __restrict__ Af8) {
  __shared__ float partial[4][DIM];
  const int n = blockIdx.x;
  const int kk = threadIdx.x & 255;
  const int mc = threadIdx.x >> 8;  // 0..3
  float acc = 0.0f;
  for (int m = mc * 64; m < mc * 64 + 64; ++m) {
    const float sgn = (m < 128) ? 1.0f : -1.0f;
    const float ukr = sgn * Ure[m * DIM + n];
    const float uki = sgn * Uim[m * DIM + n];
    acc = fmaf(ukr, Ure[m * DIM + kk], acc);
    acc = fmaf(uki, Uim[m * DIM + kk], acc);
  }
  partial[mc][kk] = acc;
  __syncthreads();
  if (mc == 0) {
    const float v = partial[0][kk] + partial[1][kk] + partial[2][kk] + partial[3][kk];
    const int nt = n >> 4, c = n & 15;
    const int t = kk >> 5, tp = t >> 1, pr = t & 1;
    const int q = (kk >> 3) & 3, j = kk & 7;
    const int off = (((nt * 4 + tp) * 4 + q) * 16 + c) * 16 + pr * 8 + j;
    const int pk = __builtin_amdgcn_cvt_pk_fp8_f32(v, v, 0, false);
    Af8[off] = (unsigned char)(pk & 0xff);
  }
}

// ---------------------------------------------------------------------------
// Kernel 3 (fp8 MFMA, A fully LDS-resident): 512-thread blocks (8 waves),
// grid 512, 2 blocks/CU (64 KB LDS each) = 16 waves/CU = 4 waves/SIMD — the
// proven high-TLP regime. A (64 KB e4m3) is staged ONCE per block via
// global_load_lds, one __syncthreads, then the batch loop runs with ZERO
// further barriers and ZERO restaging (vs 268 MB restaged in rounds 5-8).
// Each wave: 2 iters x 16 batch (b = blk*256 + w*32 + it*16 + c).
// Per n-tile: 4 ds_read_b128 -> 8 fp8 MFMAs (b128 feeds 2 k-blocks) ->
// LDS reads halve vs bf16: 536 MB chip-wide ~ 6.8 us floor.
// Live set ~50 VGPR (psi fp8 = 8 x i64 = 16) -> fits the 64-VGPR pin.
// psi_b[k] = g[k>>4]*h[k&15], quantized e4m3 via v_cvt_pk_fp8_f32 (RNE).
// Epilogue identical to verified bf16 path (C/D layout dtype-independent).
// ---------------------------------------------------------------------------
__global__ __launch_bounds__(512) void qcnn_mfma(const float* __restrict__ x,
                                                 const unsigned char* __restrict__ Af8,
                                                 float* __restrict__ out) {
  __shared__ unsigned char sA[65536];  // full A, fp8, fragment-paired order
  const int tid = threadIdx.x;
  const int lane = tid & 63;
  const int w = __builtin_amdgcn_readfirstlane(tid >> 6);  // 0..7
  const int c = lane & 15;
  const int q = lane >> 4;
  const int lo = q & 1;
  const int hi = (q >> 1) & 1;
  const int bblock = blockIdx.x * 256;

  // stage full A once: 8 x 8 KB, block-cooperative, 16 B per thread per step
#pragma unroll
  for (int i = 0; i < 8; ++i) {
    __builtin_amdgcn_global_load_lds(
        (const __attribute__((address_space(1))) uint32_t*)(Af8 + i * 8192 +
                                                            w * 1024 + lane * 16),
        (__attribute__((address_space(3))) uint32_t*)(sA + i * 8192 + w * 1024),
        16, 0, 0);
  }
  __syncthreads();  // the only barrier in this kernel

#pragma unroll 1
  for (int it = 0; it < 2; ++it) {
    const int b = bblock + w * 32 + it * 16 + c;
    const float4* xv = (const float4*)(x + (size_t)b * 8);
    const float4 x0 = xv[0];
    const float4 x1 = xv[1];
    const float xs[8] = {x0.x, x0.y, x0.z, x0.w, x1.x, x1.y, x1.z, x1.w};
    float cc[8], ss[8];
#pragma unroll
    for (int u = 0; u < 8; ++u) {
      cc[u] = __cosf(0.5f * xs[u]);
      ss[u] = __sinf(0.5f * xs[u]);
    }
    // hs[j] = h[8*lo + j]
    float hs[8];
    {
      const float a = lo ? ss[4] : cc[4];
      const float b0 = a * cc[5], b1 = a * ss[5];
      const float c0 = b0 * cc[6], c1 = b0 * ss[6];
      const float c2 = b1 * cc[6], c3 = b1 * ss[6];
      hs[0] = c0 * cc[7]; hs[1] = c0 * ss[7];
      hs[2] = c1 * cc[7]; hs[3] = c1 * ss[7];
      hs[4] = c2 * cc[7]; hs[5] = c2 * ss[7];
      hs[6] = c3 * cc[7]; hs[7] = c3 * ss[7];
    }
    // gk[t] = g[2t + hi]
    float gk[8];
    {
      const float g3 = hi ? ss[3] : cc[3];
      const float d0 = cc[2] * g3, d1 = ss[2] * g3;
      const float e0 = cc[1] * d0, e1 = cc[1] * d1;
      const float e2 = ss[1] * d0, e3 = ss[1] * d1;
      gk[0] = cc[0] * e0; gk[1] = cc[0] * e1;
      gk[2] = cc[0] * e2; gk[3] = cc[0] * e3;
      gk[4] = ss[0] * e0; gk[5] = ss[0] * e1;
      gk[6] = ss[0] * e2; gk[7] = ss[0] * e3;
    }
    // hd[r] = h[8*hi + 4*lo + r]
    float hd[4];
    {
      const float head = (hi ? ss[4] : cc[4]) * (lo ? ss[5] : cc[5]);
      const float h0 = head * cc[6], h1 = head * ss[6];
      hd[0] = h0 * cc[7]; hd[1] = h0 * ss[7];
      hd[2] = h1 * cc[7]; hd[3] = h1 * ss[7];
    }
    // psi frag for k-block t, element j: psi_b[32t + 8q + j] = gk[t]*hs[j],
    // packed e4m3: byte j of i64. cvt_pk writes (lo byte = src0).
    long psi[8];
#pragma unroll
    for (int t = 0; t < 8; ++t) {
      int plo = __builtin_amdgcn_cvt_pk_fp8_f32(gk[t] * hs[0], gk[t] * hs[1], 0, false);
      plo = __builtin_amdgcn_cvt_pk_fp8_f32(gk[t] * hs[2], gk[t] * hs[3], plo, true);
      int phi = __builtin_amdgcn_cvt_pk_fp8_f32(gk[t] * hs[4], gk[t] * hs[5], 0, false);
      phi = __builtin_amdgcn_cvt_pk_fp8_f32(gk[t] * hs[6], gk[t] * hs[7], phi, true);
      psi[t] = (long)(((unsigned long)(unsigned)phi << 32) | (unsigned)plo);
    }

    float z = 0.0f;
#pragma unroll
    for (int nt = 0; nt < 16; ++nt) {
      f32x4 acc = {0.0f, 0.0f, 0.0f, 0.0f};
#pragma unroll
      for (int tp = 0; tp < 4; ++tp) {
        const lng2 av = *(const lng2*)(sA + nt * 4096 + tp * 1024 + lane * 16);
        acc = __builtin_amdgcn_mfma_f32_16x16x32_fp8_fp8(av.x, psi[2 * tp], acc, 0, 0, 0);
        acc = __builtin_amdgcn_mfma_f32_16x16x32_fp8_fp8(av.y, psi[2 * tp + 1], acc, 0, 0, 0);
      }
      // rows n = nt*16 + q*4 + r -> psi[b][n] = g[nt] * hd[r], nt compile-time
      const float gv = ((nt & 8) ? ss[0] : cc[0]) * ((nt & 4) ? ss[1] : cc[1]) *
                       ((nt & 2) ? ss[2] : cc[2]) * ((nt & 1) ? ss[3] : cc[3]);
      const float dot =
          hd[0] * acc[0] + hd[1] * acc[1] + hd[2] * acc[2] + hd[3] * acc[3];
      z = fmaf(gv, dot, z);
    }

    // reduce across the 4 q-groups (same col lives in lanes c+16m)
    z += __shfl_xor(z, 16);
    z += __shfl_xor(z, 32);
    if (lane < 16) {
      out[bblock + w * 32 + it * 16 + lane] = 1.0f / (1.0f + __expf(-z));
    }
  }
}

// ---------------------------------------------------------------------------
// ws layout: Ure[65536] f32 | Uim[65536] f32 | Af8[65536] e4m3  = 576 KB.
// ---------------------------------------------------------------------------
extern "C" void kernel_launch(void* const* d_in, const int* in_sizes, int n_in,
                              void* d_out, int out_size, void* d_ws, size_t ws_size,
                              hipStream_t stream) {
  const float* x = (const float*)d_in[0];
  const float* params = (const float*)d_in[1];
  float* out = (float*)d_out;
  float* Ure = (float*)d_ws;
  float* Uim = Ure + DIM * DIM;
  unsigned char* Af8 = (unsigned char*)(Uim + DIM * DIM);

  build_U<<<DIM, 64, 0, stream>>>(params, Ure, Uim);
  build_A<<<DIM, 1024, 0, stream>>>(Ure, Uim, Af8);

  const int B = in_sizes[0] / NQ;  // 131072
  qcnn_mfma<<<B / 256, 512, 0, stream>>>(x, Af8, out);
}

// Round 10
// 83.705 us; speedup vs baseline: 1.1993x; 1.1993x over previous
//
#include <hip/hip_runtime.h>
#include <stdint.h>

#define DIM 256
#define NQ 8
#define NLAYERS 3
#define NPAIRS 4

typedef float f32x4 __attribute__((ext_vector_type(4)));
typedef long lng2 __attribute__((ext_vector_type(2)));  // 16 B = two i64 fp8 frags

// ---------------------------------------------------------------------------
// Kernel 1: build U (256x256 complex fp32), barrier-free, one WAVE per basis
// column, one column per 64-thread block. Lane holds 4 amplitudes
// a = r*64 + lane. Wire w <-> bit (7-w) of a: wire0 -> r bit1, wire1 -> r
// bit0 (in-register), wire2..7 -> lane bits 5..0 (shfl_xor).
// Algebra verified rounds 6-9 (passed).
// ---------------------------------------------------------------------------
__global__ __launch_bounds__(64) void build_U(const float* __restrict__ params,
                                              float* __restrict__ Ure,
                                              float* __restrict__ Uim) {
  const int lane = threadIdx.x;
  const int col = blockIdx.x;

  float ar[4], ai[4];
#pragma unroll
  for (int r = 0; r < 4; ++r) {
    ar[r] = (r * 64 + lane == col) ? 1.0f : 0.0f;
    ai[r] = 0.0f;
  }

  for (int layer = 0; layer < NLAYERS; ++layer) {
#pragma unroll
    for (int p = 0; p < NPAIRS; ++p) {
      const int base = (layer * NPAIRS + p) * 4;
      const float p0 = params[base + 0], p1 = params[base + 1];
      const float p2 = params[base + 2], p3 = params[base + 3];
      const int czm = (p == 1) ? 32 : (p == 2) ? 8 : 2;   // ctrl / RZ_i bit
      const int txr = (p == 1) ? 16 : (p == 2) ? 4 : 1;   // target xor / bit

      { // RZ(p0) on wire i = 2p
        float s0, c0;
        __sincosf(0.5f * p0, &s0, &c0);
        if (p == 0) {
#pragma unroll
          for (int r = 0; r < 4; ++r) {
            const float sg = (r >= 2) ? s0 : -s0;  // r bit1
            const float nr = ar[r] * c0 - ai[r] * sg;
            ai[r] = ar[r] * sg + ai[r] * c0;
            ar[r] = nr;
          }
        } else {
          const float sg = (lane & czm) ? s0 : -s0;
#pragma unroll
          for (int r = 0; r < 4; ++r) {
            const float nr = ar[r] * c0 - ai[r] * sg;
            ai[r] = ar[r] * sg + ai[r] * c0;
            ar[r] = nr;
          }
        }
      }
      { // RX(p1) on wire j = 2p+1
        float s0, c0;
        __sincosf(0.5f * p1, &s0, &c0);
        if (p == 0) {  // partner r^1
          float nr[4], ni[4];
#pragma unroll
          for (int r = 0; r < 4; ++r) {
            nr[r] = c0 * ar[r] + s0 * ai[r ^ 1];
            ni[r] = c0 * ai[r] - s0 * ar[r ^ 1];
          }
#pragma unroll
          for (int r = 0; r < 4; ++r) { ar[r] = nr[r]; ai[r] = ni[r]; }
        } else {  // partner lane^txr
#pragma unroll
          for (int r = 0; r < 4; ++r) {
            const float pr = __shfl_xor(ar[r], txr);
            const float pi = __shfl_xor(ai[r], txr);
            ar[r] = c0 * ar[r] + s0 * pi;
            ai[r] = c0 * ai[r] - s0 * pr;
          }
        }
      }
      { // CNOT(i -> j)
        if (p == 0) {  // ctrl r bit1: swap amp[2] <-> amp[3]
          const float tr = ar[2], ti = ai[2];
          ar[2] = ar[3]; ai[2] = ai[3];
          ar[3] = tr;    ai[3] = ti;
        } else {
#pragma unroll
          for (int r = 0; r < 4; ++r) {
            const float vr = __shfl_xor(ar[r], txr);
            const float vi = __shfl_xor(ai[r], txr);
            ar[r] = (lane & czm) ? vr : ar[r];
            ai[r] = (lane & czm) ? vi : ai[r];
          }
        }
      }
      { // RZ(p2) on wire j
        float s0, c0;
        __sincosf(0.5f * p2, &s0, &c0);
        if (p == 0) {
#pragma unroll
          for (int r = 0; r < 4; ++r) {
            const float sg = (r & 1) ? s0 : -s0;  // r bit0
            const float nr = ar[r] * c0 - ai[r] * sg;
            ai[r] = ar[r] * sg + ai[r] * c0;
            ar[r] = nr;
          }
        } else {
          const float sg = (lane & txr) ? s0 : -s0;
#pragma unroll
          for (int r = 0; r < 4; ++r) {
            const float nr = ar[r] * c0 - ai[r] * sg;
            ai[r] = ar[r] * sg + ai[r] * c0;
            ar[r] = nr;
          }
        }
      }
      { // RX(p3) on wire j
        float s0, c0;
        __sincosf(0.5f * p3, &s0, &c0);
        if (p == 0) {
          float nr[4], ni[4];
#pragma unroll
          for (int r = 0; r < 4; ++r) {
            nr[r] = c0 * ar[r] + s0 * ai[r ^ 1];
            ni[r] = c0 * ai[r] - s0 * ar[r ^ 1];
          }
#pragma unroll
          for (int r = 0; r < 4; ++r) { ar[r] = nr[r]; ai[r] = ni[r]; }
        } else {
#pragma unroll
          for (int r = 0; r < 4; ++r) {
            const float pr = __shfl_xor(ar[r], txr);
            const float pi = __shfl_xor(ai[r], txr);
            ar[r] = c0 * ar[r] + s0 * pi;
            ai[r] = c0 * ai[r] - s0 * pr;
          }
        }
      }
    }
  }
#pragma unroll
  for (int r = 0; r < 4; ++r) {
    Ure[(r * 64 + lane) * DIM + col] = ar[r];
    Uim[(r * 64 + lane) * DIM + col] = ai[r];
  }
}

// ---------------------------------------------------------------------------
// Kernel 2: A[n][k] = Re(U^H D U)[n][k], fp8 e4m3 (|A|<=1, RNE HW cvt), in
// PAIRED fragment order so one ds_read_b128 yields the A-fragments of TWO
// k-blocks (t=2tp, 2tp+1)  [verified round 9: absmax 0.0117 passes]:
//   nt=n>>4, c=n&15, t=k>>5, tp=t>>1, pr=t&1, q=(k>>3)&3, j=k&7
//   off = (((nt*4 + tp)*4 + q)*16 + c)*16 + pr*8 + j         (64 KB total)
// ---------------------------------------------------------------------------
__global__ __launch_bounds__(1024) void build_A(const float* __restrict__ Ure,
                                                const float* __restrict__ Uim,
                                                unsigned char* __restrict__ Af8) {
  __shared__ float partial[4][DIM];
  const int n = blockIdx.x;
  const int kk = threadIdx.x & 255;
  const int mc = threadIdx.x >> 8;  // 0..3
  float acc = 0.0f;
  for (int m = mc * 64; m < mc * 64 + 64; ++m) {
    const float sgn = (m < 128) ? 1.0f : -1.0f;
    const float ukr = sgn * Ure[m * DIM + n];
    const float uki = sgn * Uim[m * DIM + n];
    acc = fmaf(ukr, Ure[m * DIM + kk], acc);
    acc = fmaf(uki, Uim[m * DIM + kk], acc);
  }
  partial[mc][kk] = acc;
  __syncthreads();
  if (mc == 0) {
    const float v = partial[0][kk] + partial[1][kk] + partial[2][kk] + partial[3][kk];
    const int nt = n >> 4, c = n & 15;
    const int t = kk >> 5, tp = t >> 1, pr = t & 1;
    const int q = (kk >> 3) & 3, j = kk & 7;
    const int off = (((nt * 4 + tp) * 4 + q) * 16 + c) * 16 + pr * 8 + j;
    const int pk = __builtin_amdgcn_cvt_pk_fp8_f32(v, v, 0, false);
    Af8[off] = (unsigned char)(pk & 0xff);
  }
}

// ---------------------------------------------------------------------------
// Kernel 3 (fp8 MFMA, A fully LDS-resident, v2): structure verified round 9
// (absmax 0.0117); v2 fixes the round-9 spill (48.9 MB scratch writes at
// VGPR=128). Cause: with no barriers in the body, the fully-unrolled 16-tile
// loop let the scheduler hoist all 64 ds_read_b128 -> 256 VGPRs of in-flight
// loads. Fix: real backedge every 4 tiles (#pragma unroll 1 on nt0) bounds
// hoisting to 16 loads = 64 VGPRs; live set ~120 < 128 cap -> spill-free.
// 512-thread blocks, grid 512, 2 blocks/CU (64 KB LDS) = 16 waves/CU.
// Floor: max(MFMA ~8.3us, LDS 536 MB ~6.8us) ~ 9-11us.
// ---------------------------------------------------------------------------
__global__ __launch_bounds__(512) void qcnn_mfma(const float* __restrict__ x,
                                                 const unsigned char* __restrict__ Af8,
                                                 float* __restrict__ out) {
  __shared__ unsigned char sA[65536];  // full A, fp8, fragment-paired order
  const int tid = threadIdx.x;
  const int lane = tid & 63;
  const int w = __builtin_amdgcn_readfirstlane(tid >> 6);  // 0..7
  const int c = lane & 15;
  const int q = lane >> 4;
  const int lo = q & 1;
  const int hi = (q >> 1) & 1;
  const int bblock = blockIdx.x * 256;

  // stage full A once: 8 x 8 KB, block-cooperative, 16 B per thread per step
#pragma unroll
  for (int i = 0; i < 8; ++i) {
    __builtin_amdgcn_global_load_lds(
        (const __attribute__((address_space(1))) uint32_t*)(Af8 + i * 8192 +
                                                            w * 1024 + lane * 16),
        (__attribute__((address_space(3))) uint32_t*)(sA + i * 8192 + w * 1024),
        16, 0, 0);
  }
  __syncthreads();  // the only barrier in this kernel

#pragma unroll 1
  for (int it = 0; it < 2; ++it) {
    const int b = bblock + w * 32 + it * 16 + c;
    const float4* xv = (const float4*)(x + (size_t)b * 8);
    const float4 x0 = xv[0];
    const float4 x1 = xv[1];
    const float xs[8] = {x0.x, x0.y, x0.z, x0.w, x1.x, x1.y, x1.z, x1.w};
    float cc[8], ss[8];
#pragma unroll
    for (int u = 0; u < 8; ++u) {
      cc[u] = __cosf(0.5f * xs[u]);
      ss[u] = __sinf(0.5f * xs[u]);
    }
    // hs[j] = h[8*lo + j]
    float hs[8];
    {
      const float a = lo ? ss[4] : cc[4];
      const float b0 = a * cc[5], b1 = a * ss[5];
      const float c0 = b0 * cc[6], c1 = b0 * ss[6];
      const float c2 = b1 * cc[6], c3 = b1 * ss[6];
      hs[0] = c0 * cc[7]; hs[1] = c0 * ss[7];
      hs[2] = c1 * cc[7]; hs[3] = c1 * ss[7];
      hs[4] = c2 * cc[7]; hs[5] = c2 * ss[7];
      hs[6] = c3 * cc[7]; hs[7] = c3 * ss[7];
    }
    // gk[t] = g[2t + hi]
    float gk[8];
    {
      const float g3 = hi ? ss[3] : cc[3];
      const float d0 = cc[2] * g3, d1 = ss[2] * g3;
      const float e0 = cc[1] * d0, e1 = cc[1] * d1;
      const float e2 = ss[1] * d0, e3 = ss[1] * d1;
      gk[0] = cc[0] * e0; gk[1] = cc[0] * e1;
      gk[2] = cc[0] * e2; gk[3] = cc[0] * e3;
      gk[4] = ss[0] * e0; gk[5] = ss[0] * e1;
      gk[6] = ss[0] * e2; gk[7] = ss[0] * e3;
    }
    // hd[r] = h[8*hi + 4*lo + r]
    float hd[4];
    {
      const float head = (hi ? ss[4] : cc[4]) * (lo ? ss[5] : cc[5]);
      const float h0 = head * cc[6], h1 = head * ss[6];
      hd[0] = h0 * cc[7]; hd[1] = h0 * ss[7];
      hd[2] = h1 * cc[7]; hd[3] = h1 * ss[7];
    }
    // psi frag for k-block t, element j: psi_b[32t + 8q + j] = gk[t]*hs[j],
    // packed e4m3 bytes of an i64 (cvt_pk: lo byte = src0).
    long psi[8];
#pragma unroll
    for (int t = 0; t < 8; ++t) {
      int plo = __builtin_amdgcn_cvt_pk_fp8_f32(gk[t] * hs[0], gk[t] * hs[1], 0, false);
      plo = __builtin_amdgcn_cvt_pk_fp8_f32(gk[t] * hs[2], gk[t] * hs[3], plo, true);
      int phi = __builtin_amdgcn_cvt_pk_fp8_f32(gk[t] * hs[4], gk[t] * hs[5], 0, false);
      phi = __builtin_amdgcn_cvt_pk_fp8_f32(gk[t] * hs[6], gk[t] * hs[7], phi, true);
      psi[t] = (long)(((unsigned long)(unsigned)phi << 32) | (unsigned)plo);
    }

    float z = 0.0f;
#pragma unroll 1
    for (int nt0 = 0; nt0 < 4; ++nt0) {  // REAL backedge: bounds load hoisting
      const float ga = (nt0 & 2) ? ss[0] : cc[0];   // uniform runtime select
      const float gb = (nt0 & 1) ? ss[1] : cc[1];
      const float gab = ga * gb;
#pragma unroll
      for (int u = 0; u < 4; ++u) {  // nt = nt0*4 + u (u compile-time)
        f32x4 acc = {0.0f, 0.0f, 0.0f, 0.0f};
#pragma unroll
        for (int tp = 0; tp < 4; ++tp) {
          const lng2 av =
              *(const lng2*)(sA + nt0 * 16384 + u * 4096 + tp * 1024 + lane * 16);
          acc = __builtin_amdgcn_mfma_f32_16x16x32_fp8_fp8(av.x, psi[2 * tp], acc, 0, 0, 0);
          acc = __builtin_amdgcn_mfma_f32_16x16x32_fp8_fp8(av.y, psi[2 * tp + 1], acc, 0, 0, 0);
        }
        // rows n = nt*16 + q*4 + r -> psi[b][n] = g[nt] * hd[r]
        const float gv = gab * ((u & 2) ? ss[2] : cc[2]) * ((u & 1) ? ss[3] : cc[3]);
        const float dot =
            hd[0] * acc[0] + hd[1] * acc[1] + hd[2] * acc[2] + hd[3] * acc[3];
        z = fmaf(gv, dot, z);
      }
    }

    // reduce across the 4 q-groups (same col lives in lanes c+16m)
    z += __shfl_xor(z, 16);
    z += __shfl_xor(z, 32);
    if (lane < 16) {
      out[bblock + w * 32 + it * 16 + lane] = 1.0f / (1.0f + __expf(-z));
    }
  }
}

// ---------------------------------------------------------------------------
// ws layout: Ure[65536] f32 | Uim[65536] f32 | Af8[65536] e4m3  = 576 KB.
// ---------------------------------------------------------------------------
extern "C" void kernel_launch(void* const* d_in, const int* in_sizes, int n_in,
                              void* d_out, int out_size, void* d_ws, size_t ws_size,
                              hipStream_t stream) {
  const float* x = (const float*)d_in[0];
  const float* params = (const float*)d_in[1];
  float* out = (float*)d_out;
  float* Ure = (float*)d_ws;
  float* Uim = Ure + DIM * DIM;
  unsigned char* Af8 = (unsigned char*)(Uim + DIM * DIM);

  build_U<<<DIM, 64, 0, stream>>>(params, Ure, Uim);
  build_A<<<DIM, 1024, 0, stream>>>(Ure, Uim, Af8);

  const int B = in_sizes[0] / NQ;  // 131072
  qcnn_mfma<<<B / 256, 512, 0, stream>>>(x, Af8, out);
}